// Round 13
// baseline (534.928 us; speedup 1.0000x reference)
//
#include <hip/hip_runtime.h>

#define NF 40
#define NF4 10
#define H  64
#define NC 3
#define BK 256        // nodes per bucket (dst>>8)
#define CAP 10240     // staging capacity per bucket (mean 8192, +22 sigma)
#define MAXNBK 512
#define SMASK 0xFFFFFu
#define EPB 6400      // edges per k_bin2 block
#define NSL 8         // src slices
#define SSH 14        // slice = src>>14: 16384 rows = 2.6 MB of xs (fits 4 MB L2)
#define SPIN 150      // bounded soft-barrier spin (deadlock-free)
#define PHB 768       // k_pull1_ph grid: 768x512 = 3 blocks/CU, all co-resident

__device__ __forceinline__ void add4(float4& a, const float4& u) {
    a.x += u.x; a.y += u.y; a.z += u.z; a.w += u.w;
}
__device__ __forceinline__ void add4b(float4& a, const float4& u, const float4& w) {
    a.x += u.x + w.x; a.y += u.y + w.y; a.z += u.z + w.z; a.w += u.w + w.w;
}
__device__ __forceinline__ float4 fin4(float dd, const float4& a, const float4& s) {
    return make_float4(dd * (a.x + s.x), dd * (a.y + s.y),
                       dd * (a.z + s.z), dd * (a.w + s.w));
}

// --- zero ints ---
__global__ void k_zero(int* __restrict__ p, int n) {
    int i = blockIdx.x * blockDim.x + threadIdx.x;
    if (i < n) p[i] = 0;
}

// --- partition: block-local bucket sort in LDS, then coalesced window writes ---
__global__ __launch_bounds__(512) void k_bin2(const int* __restrict__ src,
                                              const int* __restrict__ dst,
                                              int* __restrict__ gcur,
                                              unsigned* __restrict__ staging,
                                              int ne, int nbk) {
    __shared__ unsigned sorted[EPB];               // 25.6 KB
    __shared__ unsigned short sbk[EPB];            // 12.8 KB
    __shared__ int cnt[MAXNBK];
    __shared__ int tsum[MAXNBK];
    __shared__ int lstart[MAXNBK];
    __shared__ int gbase[MAXNBK];
    __shared__ int cur[MAXNBK];
    int t = threadIdx.x;
    int e0 = blockIdx.x * EPB;
    int m = min(EPB, ne - e0);
    if (m <= 0) return;

    for (int b = t; b < MAXNBK; b += 512) cnt[b] = 0;
    __syncthreads();
    for (int j = t; j < m; j += 512)               // pass 1: bucket histogram
        atomicAdd(&cnt[dst[e0 + j] >> 8], 1);
    __syncthreads();
    int val = (t < nbk) ? cnt[t] : 0;              // block-wide exclusive scan (512)
    tsum[t] = val;
    __syncthreads();
    for (int off = 1; off < 512; off <<= 1) {
        int a = (t >= off) ? tsum[t - off] : 0;
        __syncthreads();
        tsum[t] += a;
        __syncthreads();
    }
    lstart[t] = tsum[t] - val;
    cur[t] = tsum[t] - val;
    if (t < nbk) gbase[t] = val ? atomicAdd(&gcur[t], val) : 0;   // reserve windows
    __syncthreads();
    for (int j = t; j < m; j += 512) {             // pass 2: LDS scatter (bucket order)
        int d = dst[e0 + j], s = src[e0 + j];
        int b = d >> 8;
        int p = atomicAdd(&cur[b], 1);
        sorted[p] = ((unsigned)(d & 255) << 20) | (unsigned)s;
        sbk[p] = (unsigned short)b;
    }
    __syncthreads();
    for (int j = t; j < m; j += 512) {             // pass 3: near-coalesced writes
        int b = sbk[j];
        staging[(size_t)b * CAP + gbase[b] + (j - lstart[b])] = sorted[j];
    }
}

// --- per-bucket sort by (dlocal, src-slice); emits rs/rl/dinv (+sseg if provided) ---
__global__ __launch_bounds__(512) void k_sort(unsigned* __restrict__ staging,
                                              const int* __restrict__ gcur,
                                              int* __restrict__ rs, int* __restrict__ rl,
                                              float* __restrict__ dinv,
                                              int* __restrict__ sseg, int n) {
    __shared__ unsigned buf[CAP];      // 40 KB bounce buffer
    __shared__ int cnt[BK * NSL];      // 8 KB: histogram -> starts -> cursors
    __shared__ int tsum[512];
    int b = blockIdx.x, t = threadIdx.x;
    int ebase = b * CAP;
    int rlen = gcur[b];
    for (int j = t; j < rlen; j += 512) buf[j] = staging[ebase + j];
    for (int i = t; i < BK * NSL; i += 512) cnt[i] = 0;
    __syncthreads();
    for (int j = t; j < rlen; j += 512) {
        unsigned e = buf[j];
        int key = (int)((e >> 20) * NSL) + (int)((e & SMASK) >> SSH);
        atomicAdd(&cnt[key], 1);
    }
    __syncthreads();
    // exclusive scan of cnt[2048]: per-thread serial 4 + Hillis-Steele over 512 totals
    int base4 = t * 4;
    int loc[4]; int run = 0;
    #pragma unroll
    for (int i = 0; i < 4; ++i) { loc[i] = run; run += cnt[base4 + i]; }
    tsum[t] = run;
    __syncthreads();
    for (int off = 1; off < 512; off <<= 1) {
        int a = (t >= off) ? tsum[t - off] : 0;
        __syncthreads();
        tsum[t] += a;
        __syncthreads();
    }
    int texcl = tsum[t] - run;
    #pragma unroll
    for (int i = 0; i < 4; ++i) cnt[base4 + i] = texcl + loc[i];
    __syncthreads();
    if (t < BK) {                                  // rs/rl/dinv/sseg before cursors bump
        int node = b * BK + t;
        int st0 = cnt[t * NSL];
        int en0 = (t == BK - 1) ? rlen : cnt[(t + 1) * NSL];
        int deg = en0 - st0;
        if (node < n) {
            rs[node] = ebase + st0;
            rl[node] = deg;
            dinv[node] = rsqrtf((float)(deg + 1));
            if (sseg) {
                #pragma unroll
                for (int s = 0; s < NSL; ++s)
                    sseg[(size_t)node * NSL + s] = ebase + cnt[t * NSL + s];
            }
        }
    }
    __syncthreads();
    for (int j = t; j < rlen; j += 512) {          // scatter back sorted
        unsigned e = buf[j];
        int key = (int)((e >> 20) * NSL) + (int)((e & SMASK) >> SSH);
        int p = atomicAdd(&cnt[key], 1);
        staging[ebase + p] = e;
    }
}

// --- xs[s] = x[s] * dinv[s]: hoists the per-edge dinv multiply out of pull1 ---
__global__ __launch_bounds__(256) void k_scale(const float4* __restrict__ x4,
                                               const float* __restrict__ dinv,
                                               float4* __restrict__ xs4, int total) {
    int i = blockIdx.x * blockDim.x + threadIdx.x;
    if (i < total) {
        float dd = dinv[i / NF4];
        float4 v = x4[i];
        xs4[i] = make_float4(v.x * dd, v.y * dd, v.z * dd, v.w * dd);
    }
}

// --- bounded soft grid barrier: arrive + spin; deadlock-free (bounded) ---
__device__ __forceinline__ void soft_barrier(int* c, int target) {
    __syncthreads();
    if (threadIdx.x == 0) {
        atomicAdd(c, 1);
        for (int i = 0; i < SPIN; ++i) {
            if (atomicAdd(c, 0) >= target) break;
            __builtin_amdgcn_s_sleep(2);
        }
    }
    __syncthreads();
}

// --- pull conv1, slice-phased, 4 threads/node (disjoint feature columns) ---
// Thread k of a quad owns float4 columns {k, k+4, 8+k(k<2)}; no reduction needed.
// Phase sl: all 768 co-resident blocks gather only from xs slice sl (2.6 MB, L2-fits).
__global__ __launch_bounds__(512) void k_pull1_ph(
        const unsigned* __restrict__ st, const int* __restrict__ sseg,
        const int* __restrict__ rs, const int* __restrict__ rl,
        const float* __restrict__ dinv, const float4* __restrict__ xs4,
        float4* __restrict__ ax4, int* __restrict__ barr, int n) {
    int t = threadIdx.x;
    int gtid = blockIdx.x * 512 + t;
    int slot = gtid >> 2, k = gtid & 3;
    int NSLOT = (gridDim.x * 512) >> 2;            // 98304
    int tgt = gridDim.x;
    int q0 = k, q1 = k + 4, q2 = 8 + k;            // q2 only for k<2
    bool hq2 = (k < 2);

    int nd0 = slot, nd1 = slot + NSLOT;
    bool v0 = (nd0 < n), v1 = (nd1 < n);
    int lend0 = v0 ? rs[nd0] + rl[nd0] : 0;
    int lend1 = v1 ? rs[nd1] + rl[nd1] : 0;

    float4 z = make_float4(0.f, 0.f, 0.f, 0.f);
    float4 a00 = z, a01 = z, a02 = z;              // node0 acc (3 columns)
    float4 a10 = z, a11 = z, a12 = z;              // node1 acc (rarely active)

    for (int sl = 0; sl < NSL; ++sl) {
        if (v0) {
            int j = sseg[(size_t)nd0 * NSL + sl];
            int end = (sl == NSL - 1) ? lend0 : sseg[(size_t)nd0 * NSL + sl + 1];
            for (; j + 1 < end; j += 2) {          // 2 edges x 2-3 independent gathers
                int s0 = (int)(st[j] & SMASK), s1 = (int)(st[j + 1] & SMASK);
                const float4* r0 = xs4 + (size_t)s0 * NF4;
                const float4* r1 = xs4 + (size_t)s1 * NF4;
                add4b(a00, r0[q0], r1[q0]);
                add4b(a01, r0[q1], r1[q1]);
                if (hq2) add4b(a02, r0[q2], r1[q2]);
            }
            if (j < end) {
                const float4* r0 = xs4 + (size_t)(st[j] & SMASK) * NF4;
                add4(a00, r0[q0]);
                add4(a01, r0[q1]);
                if (hq2) add4(a02, r0[q2]);
            }
        }
        if (v1) {
            int j = sseg[(size_t)nd1 * NSL + sl];
            int end = (sl == NSL - 1) ? lend1 : sseg[(size_t)nd1 * NSL + sl + 1];
            for (; j + 1 < end; j += 2) {
                int s0 = (int)(st[j] & SMASK), s1 = (int)(st[j + 1] & SMASK);
                const float4* r0 = xs4 + (size_t)s0 * NF4;
                const float4* r1 = xs4 + (size_t)s1 * NF4;
                add4b(a10, r0[q0], r1[q0]);
                add4b(a11, r0[q1], r1[q1]);
                if (hq2) add4b(a12, r0[q2], r1[q2]);
            }
            if (j < end) {
                const float4* r0 = xs4 + (size_t)(st[j] & SMASK) * NF4;
                add4(a10, r0[q0]);
                add4(a11, r0[q1]);
                if (hq2) add4(a12, r0[q2]);
            }
        }
        if (sl < NSL - 1) soft_barrier(barr + sl, tgt);   // uniform participation
    }
    if (v0) {
        float dd = dinv[nd0];
        ax4[(size_t)nd0 * NF4 + q0] = fin4(dd, a00, xs4[(size_t)nd0 * NF4 + q0]);
        ax4[(size_t)nd0 * NF4 + q1] = fin4(dd, a01, xs4[(size_t)nd0 * NF4 + q1]);
        if (hq2)
            ax4[(size_t)nd0 * NF4 + q2] = fin4(dd, a02, xs4[(size_t)nd0 * NF4 + q2]);
    }
    if (v1) {
        float dd = dinv[nd1];
        ax4[(size_t)nd1 * NF4 + q0] = fin4(dd, a10, xs4[(size_t)nd1 * NF4 + q0]);
        ax4[(size_t)nd1 * NF4 + q1] = fin4(dd, a11, xs4[(size_t)nd1 * NF4 + q1]);
        if (hq2)
            ax4[(size_t)nd1 * NF4 + q2] = fin4(dd, a12, xs4[(size_t)nd1 * NF4 + q2]);
    }
}

// --- pull conv1 (xs fallback): 6 nbr slots x 10 lanes ---
__global__ __launch_bounds__(256) void k_pull1_xs(
        const unsigned* __restrict__ st, const int* __restrict__ rs,
        const int* __restrict__ rl, const float* __restrict__ dinv,
        const float4* __restrict__ xs4, float4* __restrict__ ax4, int n) {
    __shared__ float4 red[4][64];
    int t = threadIdx.x;
    int w = t >> 6, lane = t & 63;
    int d = blockIdx.x * 4 + w;
    if (d >= n) return;
    int g = lane / 10, f = lane - g * 10;
    int beg = rs[d], len = rl[d];
    float dd = dinv[d];
    float4 acc = make_float4(0.f, 0.f, 0.f, 0.f);
    if (g < 6) {
        int j = beg + g, end = beg + len;
        for (; j + 6 < end; j += 12) {
            unsigned eA = st[j], eB = st[j + 6];
            float4 a4 = xs4[(eA & SMASK) * NF4 + f];
            float4 b4 = xs4[(eB & SMASK) * NF4 + f];
            add4b(acc, a4, b4);
        }
        if (j < end) add4(acc, xs4[(st[j] & SMASK) * NF4 + f]);
    }
    red[w][lane] = acc;
    if (lane < NF4) {
        float4 tot = red[w][lane];
        #pragma unroll
        for (int gg = 1; gg < 6; ++gg) add4(tot, red[w][gg * 10 + lane]);
        ax4[d * NF4 + lane] = fin4(dd, tot, xs4[d * NF4 + lane]);
    }
}

// --- pull conv1 (no-xs fallback): dinv gathered per edge ---
__global__ __launch_bounds__(256) void k_pull1_od(
        const unsigned* __restrict__ st, const int* __restrict__ rs,
        const int* __restrict__ rl, const float* __restrict__ dinv,
        const float4* __restrict__ x4, float4* __restrict__ ax4, int n) {
    __shared__ float4 red[4][64];
    int t = threadIdx.x;
    int w = t >> 6, lane = t & 63;
    int d = blockIdx.x * 4 + w;
    if (d >= n) return;
    int g = lane / 10, f = lane - g * 10;
    int beg = rs[d], len = rl[d];
    float dd = dinv[d];
    float4 acc = make_float4(0.f, 0.f, 0.f, 0.f);
    if (g < 6) {
        int j = beg + g, end = beg + len;
        for (; j + 6 < end; j += 12) {
            unsigned eA = st[j], eB = st[j + 6];
            int sA = (int)(eA & SMASK), sB = (int)(eB & SMASK);
            float wA = dinv[sA], wB = dinv[sB];
            float4 a4 = x4[sA * NF4 + f];
            float4 b4 = x4[sB * NF4 + f];
            acc.x += a4.x * wA + b4.x * wB;
            acc.y += a4.y * wA + b4.y * wB;
            acc.z += a4.z * wA + b4.z * wB;
            acc.w += a4.w * wA + b4.w * wB;
        }
        if (j < end) {
            unsigned e = st[j];
            int s = (int)(e & SMASK);
            float wv = dinv[s];
            float4 v = x4[s * NF4 + f];
            acc.x += v.x * wv; acc.y += v.y * wv;
            acc.z += v.z * wv; acc.w += v.w * wv;
        }
    }
    red[w][lane] = acc;
    if (lane < NF4) {
        float4 tot = red[w][lane];
        #pragma unroll
        for (int gg = 1; gg < 6; ++gg) add4(tot, red[w][gg * 10 + lane]);
        float4 self = x4[d * NF4 + lane];
        float4 o;
        o.x = dd * (tot.x + self.x * dd);
        o.y = dd * (tot.y + self.y * dd);
        o.z = dd * (tot.z + self.z * dd);
        o.w = dd * (tot.w + self.w * dd);
        ax4[d * NF4 + lane] = o;
    }
}

// --- fused per-node MLP: register-tiled wave-GEMM, 32 nodes x 64 cols per wave ---
__global__ __launch_bounds__(256, 2) void k_node(
        const float4* __restrict__ ax4,
        const float* __restrict__ W1, const float* __restrict__ b1,
        const float* __restrict__ Wf, const float* __restrict__ bf,
        const float* __restrict__ W2, const float* __restrict__ dinv,
        float4* __restrict__ s2sp4, int n) {
    __shared__ float lW1[NF * H];
    __shared__ float lWf[H * H];
    __shared__ float hT[4][H * 32];
    int t = threadIdx.x, w = t >> 6, lane = t & 63;
    int r = lane & 7, c = lane >> 3;

    for (int i = t; i < NF * H; i += 256) lW1[i] = W1[i];
    for (int i = t; i < H * H;  i += 256) lWf[i] = Wf[i];
    __syncthreads();

    int nb0 = (blockIdx.x * 4 + w) * 32;
    if (nb0 >= n) return;
    int cnt = min(32, n - nb0);

    float bb[8], bfv[8], w2s[8][3];
    #pragma unroll
    for (int j = 0; j < 8; ++j) {
        bb[j]  = b1[8 * c + j];
        bfv[j] = bf[8 * c + j];
        w2s[j][0] = W2[(8 * c + j) * NC + 0];
        w2s[j][1] = W2[(8 * c + j) * NC + 1];
        w2s[j][2] = W2[(8 * c + j) * NC + 2];
    }

    float* axT = &hT[w][0];
    #pragma unroll
    for (int i = 0; i < 5; ++i) {
        int idx = lane + 64 * i;
        int no = idx / NF4, q = idx - no * NF4;
        float4 a = make_float4(0.f, 0.f, 0.f, 0.f);
        if (no < cnt) a = ax4[(size_t)(nb0 + no) * NF4 + q];
        axT[(4 * q + 0) * 32 + no] = a.x;
        axT[(4 * q + 1) * 32 + no] = a.y;
        axT[(4 * q + 2) * 32 + no] = a.z;
        axT[(4 * q + 3) * 32 + no] = a.w;
    }

    float acc[4][8];
    #pragma unroll
    for (int i = 0; i < 4; ++i)
        #pragma unroll
        for (int j = 0; j < 8; ++j) acc[i][j] = bb[j];
    for (int k = 0; k < NF; ++k) {
        float4 a   = *(const float4*)&axT[k * 32 + 4 * r];
        float4 blo = *(const float4*)&lW1[k * H + 8 * c];
        float4 bhi = *(const float4*)&lW1[k * H + 8 * c + 4];
        float av[4] = {a.x, a.y, a.z, a.w};
        float bv[8] = {blo.x, blo.y, blo.z, blo.w, bhi.x, bhi.y, bhi.z, bhi.w};
        #pragma unroll
        for (int i = 0; i < 4; ++i)
            #pragma unroll
            for (int j = 0; j < 8; ++j) acc[i][j] = fmaf(av[i], bv[j], acc[i][j]);
    }
    #pragma unroll
    for (int j = 0; j < 8; ++j) {
        float4 hv = make_float4(fmaxf(acc[0][j], 0.f), fmaxf(acc[1][j], 0.f),
                                fmaxf(acc[2][j], 0.f), fmaxf(acc[3][j], 0.f));
        *(float4*)&hT[w][(8 * c + j) * 32 + 4 * r] = hv;
    }

    float acc2[4][8];
    #pragma unroll
    for (int i = 0; i < 4; ++i)
        #pragma unroll
        for (int j = 0; j < 8; ++j) acc2[i][j] = bfv[j];
    for (int k = 0; k < H; ++k) {
        float4 a   = *(const float4*)&hT[w][k * 32 + 4 * r];
        float4 blo = *(const float4*)&lWf[k * H + 8 * c];
        float4 bhi = *(const float4*)&lWf[k * H + 8 * c + 4];
        float av[4] = {a.x, a.y, a.z, a.w};
        float bv[8] = {blo.x, blo.y, blo.z, blo.w, bhi.x, bhi.y, bhi.z, bhi.w};
        #pragma unroll
        for (int i = 0; i < 4; ++i)
            #pragma unroll
            for (int j = 0; j < 8; ++j) acc2[i][j] = fmaf(av[i], bv[j], acc2[i][j]);
    }

    float p0[4], p1[4], p2[4];
    #pragma unroll
    for (int i = 0; i < 4; ++i) { p0[i] = 0.f; p1[i] = 0.f; p2[i] = 0.f; }
    #pragma unroll
    for (int i = 0; i < 4; ++i)
        #pragma unroll
        for (int j = 0; j < 8; ++j) {
            float s = (acc2[i][j] >= 0.5f) ? 1.f : 0.f;
            p0[i] = fmaf(s, w2s[j][0], p0[i]);
            p1[i] = fmaf(s, w2s[j][1], p1[i]);
            p2[i] = fmaf(s, w2s[j][2], p2[i]);
        }
    #pragma unroll
    for (int off = 8; off < 64; off <<= 1) {
        #pragma unroll
        for (int i = 0; i < 4; ++i) {
            p0[i] += __shfl_xor(p0[i], off);
            p1[i] += __shfl_xor(p1[i], off);
            p2[i] += __shfl_xor(p2[i], off);
        }
    }
    if (c == 0) {
        #pragma unroll
        for (int i = 0; i < 4; ++i) {
            int no = 4 * r + i;
            if (no < cnt) {
                int node = nb0 + no;
                float di = dinv[node];
                s2sp4[node] = make_float4(p0[i] * di, p1[i] * di, p2[i] * di, 0.f);
            }
        }
    }
}

// --- pull conv2 + bias + filter ---
__global__ __launch_bounds__(256) void k_pull2(
        const unsigned* __restrict__ st, const int* __restrict__ rs,
        const int* __restrict__ rl, const float* __restrict__ dinv,
        const float4* __restrict__ s2sp4, const float* __restrict__ b2,
        const float* __restrict__ ef, float* __restrict__ out, int n) {
    int t = threadIdx.x;
    int w = t >> 6, lane = t & 63;
    int d = blockIdx.x * 4 + w;
    if (d >= n) return;
    int beg = rs[d], end = beg + rl[d];
    float a0 = 0.f, a1 = 0.f, a2 = 0.f;
    for (int j = beg + lane; j < end; j += 64) {
        float4 v = s2sp4[st[j] & SMASK];
        a0 += v.x; a1 += v.y; a2 += v.z;
    }
    for (int off = 32; off; off >>= 1) {
        a0 += __shfl_down(a0, off);
        a1 += __shfl_down(a1, off);
        a2 += __shfl_down(a2, off);
    }
    if (lane == 0) {
        float dd = dinv[d];
        float4 self = s2sp4[d];
        out[d * NC + 0] = (dd * (a0 + self.x) + b2[0]) * ef[0];
        out[d * NC + 1] = (dd * (a1 + self.y) + b2[1]) * ef[1];
        out[d * NC + 2] = (dd * (a2 + self.z) + b2[2]) * ef[2];
    }
}

extern "C" void kernel_launch(void* const* d_in, const int* in_sizes, int n_in,
                              void* d_out, int out_size, void* d_ws, size_t ws_size,
                              hipStream_t stream) {
    const float* x  = (const float*)d_in[0];
    const int*   ei = (const int*)d_in[1];
    const float* W1 = (const float*)d_in[2];
    const float* b1 = (const float*)d_in[3];
    const float* Wf = (const float*)d_in[4];
    const float* bf = (const float*)d_in[5];
    const float* W2 = (const float*)d_in[6];
    const float* b2 = (const float*)d_in[7];
    const float* ef = (const float*)d_in[8];

    int n  = in_sizes[0] / NF;
    int ne = in_sizes[1] / 2;
    const int* src = ei;
    const int* dst = ei + ne;
    int nbk = (n + BK - 1) >> 8;                   // 391

    auto al = [](size_t v) { return (v + 255) & ~(size_t)255; };
    char* ws = (char*)d_ws;
    size_t off = 0;
    unsigned* staging = (unsigned*)(ws + off); off += al((size_t)nbk * CAP * 4);   // 16 MB
    float*    axbuf   = (float*)(ws + off);    off += al((size_t)n * NF * 4);      // 16 MB
    float*    s2sp    = (float*)(ws + off);    off += al((size_t)n * 4 * 4);
    float*    dinv    = (float*)(ws + off);    off += al((size_t)n * 4);
    int*      rsb     = (int*)(ws + off);      off += al((size_t)n * 4);
    int*      rlb     = (int*)(ws + off);      off += al((size_t)n * 4);
    int*      gcur    = (int*)(ws + off);      off += al((size_t)(MAXNBK + NSL) * 4);
    int*      barr    = gcur + MAXNBK;
    float*    xsbuf   = (float*)(ws + off);
    size_t    need_xs = off + al((size_t)n * NF * 4);                              // ~51 MB
    int*      ssegb   = (int*)(ws + need_xs);
    size_t    need_cp = need_xs + al((size_t)n * NSL * 4);                         // ~54 MB
    bool use_xs   = (ws_size >= need_xs);
    bool use_coop = (ws_size >= need_cp);
    float* out = (float*)d_out;

    int binblocks = (ne + EPB - 1) / EPB;          // 500

    k_zero <<<(MAXNBK + NSL + 255) / 256, 256, 0, stream>>>(gcur, MAXNBK + NSL);
    k_bin2 <<<binblocks, 512, 0, stream>>>(src, dst, gcur, staging, ne, nbk);
    k_sort <<<nbk, 512, 0, stream>>>(staging, gcur, rsb, rlb, dinv,
                                     use_coop ? ssegb : (int*)nullptr, n);
    if (use_coop) {
        k_scale   <<<(n * NF4 + 255) / 256, 256, 0, stream>>>((const float4*)x, dinv,
                                                              (float4*)xsbuf, n * NF4);
        k_pull1_ph<<<PHB, 512, 0, stream>>>(staging, ssegb, rsb, rlb, dinv,
                                            (const float4*)xsbuf, (float4*)axbuf,
                                            barr, n);
    } else if (use_xs) {
        k_scale  <<<(n * NF4 + 255) / 256, 256, 0, stream>>>((const float4*)x, dinv,
                                                             (float4*)xsbuf, n * NF4);
        k_pull1_xs<<<(n + 3) / 4, 256, 0, stream>>>(staging, rsb, rlb, dinv,
                                                    (const float4*)xsbuf,
                                                    (float4*)axbuf, n);
    } else {
        k_pull1_od<<<(n + 3) / 4, 256, 0, stream>>>(staging, rsb, rlb, dinv,
                                                    (const float4*)x, (float4*)axbuf, n);
    }
    k_node <<<(n + 127) / 128, 256, 0, stream>>>(
        (const float4*)axbuf, W1, b1, Wf, bf, W2, dinv, (float4*)s2sp, n);
    k_pull2<<<(n + 3) / 4, 256, 0, stream>>>(staging, rsb, rlb, dinv, (const float4*)s2sp,
                                             b2, ef, out, n);
}

// Round 14
// 254.742 us; speedup vs baseline: 2.0999x; 2.0999x over previous
//
#include <hip/hip_runtime.h>

#define NF 40
#define NF4 10
#define H  64
#define NC 3
#define BK 256        // nodes per bucket (dst>>8)
#define CAP 10240     // staging capacity per bucket (mean 8192, +22 sigma)
#define MAXNBK 512
#define SMASK 0xFFFFFu
#define EPB 6400      // edges per k_bin2 block
#define NSL 8         // src slices
#define SSH 14        // slice = src>>14: 16384 rows = 2.6 MB of xs (fits 4 MB L2)

__device__ __forceinline__ void add4(float4& a, const float4& u) {
    a.x += u.x; a.y += u.y; a.z += u.z; a.w += u.w;
}
__device__ __forceinline__ void add4b(float4& a, const float4& u, const float4& w) {
    a.x += u.x + w.x; a.y += u.y + w.y; a.z += u.z + w.z; a.w += u.w + w.w;
}
__device__ __forceinline__ float4 fin4(float dd, const float4& a, const float4& s) {
    return make_float4(dd * (a.x + s.x), dd * (a.y + s.y),
                       dd * (a.z + s.z), dd * (a.w + s.w));
}

// --- zero ints ---
__global__ void k_zero(int* __restrict__ p, int n) {
    int i = blockIdx.x * blockDim.x + threadIdx.x;
    if (i < n) p[i] = 0;
}

// --- partition: block-local bucket sort in LDS, then coalesced window writes ---
__global__ __launch_bounds__(512) void k_bin2(const int* __restrict__ src,
                                              const int* __restrict__ dst,
                                              int* __restrict__ gcur,
                                              unsigned* __restrict__ staging,
                                              int ne, int nbk) {
    __shared__ unsigned sorted[EPB];               // 25.6 KB
    __shared__ unsigned short sbk[EPB];            // 12.8 KB
    __shared__ int cnt[MAXNBK];
    __shared__ int tsum[MAXNBK];
    __shared__ int lstart[MAXNBK];
    __shared__ int gbase[MAXNBK];
    __shared__ int cur[MAXNBK];
    int t = threadIdx.x;
    int e0 = blockIdx.x * EPB;
    int m = min(EPB, ne - e0);
    if (m <= 0) return;

    for (int b = t; b < MAXNBK; b += 512) cnt[b] = 0;
    __syncthreads();
    for (int j = t; j < m; j += 512)               // pass 1: bucket histogram
        atomicAdd(&cnt[dst[e0 + j] >> 8], 1);
    __syncthreads();
    int val = (t < nbk) ? cnt[t] : 0;              // block-wide exclusive scan (512)
    tsum[t] = val;
    __syncthreads();
    for (int off = 1; off < 512; off <<= 1) {
        int a = (t >= off) ? tsum[t - off] : 0;
        __syncthreads();
        tsum[t] += a;
        __syncthreads();
    }
    lstart[t] = tsum[t] - val;
    cur[t] = tsum[t] - val;
    if (t < nbk) gbase[t] = val ? atomicAdd(&gcur[t], val) : 0;   // reserve windows
    __syncthreads();
    for (int j = t; j < m; j += 512) {             // pass 2: LDS scatter (bucket order)
        int d = dst[e0 + j], s = src[e0 + j];
        int b = d >> 8;
        int p = atomicAdd(&cur[b], 1);
        sorted[p] = ((unsigned)(d & 255) << 20) | (unsigned)s;
        sbk[p] = (unsigned short)b;
    }
    __syncthreads();
    for (int j = t; j < m; j += 512) {             // pass 3: near-coalesced writes
        int b = sbk[j];
        staging[(size_t)b * CAP + gbase[b] + (j - lstart[b])] = sorted[j];
    }
}

// --- per-bucket sort by (dlocal, src-slice); emits rs/rl/dinv (+sseg if provided) ---
__global__ __launch_bounds__(512) void k_sort(unsigned* __restrict__ staging,
                                              const int* __restrict__ gcur,
                                              int* __restrict__ rs, int* __restrict__ rl,
                                              float* __restrict__ dinv,
                                              int* __restrict__ sseg, int n) {
    __shared__ unsigned buf[CAP];      // 40 KB bounce buffer
    __shared__ int cnt[BK * NSL];      // 8 KB: histogram -> starts -> cursors
    __shared__ int tsum[512];
    int b = blockIdx.x, t = threadIdx.x;
    int ebase = b * CAP;
    int rlen = gcur[b];
    for (int j = t; j < rlen; j += 512) buf[j] = staging[ebase + j];
    for (int i = t; i < BK * NSL; i += 512) cnt[i] = 0;
    __syncthreads();
    for (int j = t; j < rlen; j += 512) {
        unsigned e = buf[j];
        int key = (int)((e >> 20) * NSL) + (int)((e & SMASK) >> SSH);
        atomicAdd(&cnt[key], 1);
    }
    __syncthreads();
    // exclusive scan of cnt[2048]: per-thread serial 4 + Hillis-Steele over 512 totals
    int base4 = t * 4;
    int loc[4]; int run = 0;
    #pragma unroll
    for (int i = 0; i < 4; ++i) { loc[i] = run; run += cnt[base4 + i]; }
    tsum[t] = run;
    __syncthreads();
    for (int off = 1; off < 512; off <<= 1) {
        int a = (t >= off) ? tsum[t - off] : 0;
        __syncthreads();
        tsum[t] += a;
        __syncthreads();
    }
    int texcl = tsum[t] - run;
    #pragma unroll
    for (int i = 0; i < 4; ++i) cnt[base4 + i] = texcl + loc[i];
    __syncthreads();
    if (t < BK) {                                  // rs/rl/dinv/sseg before cursors bump
        int node = b * BK + t;
        int st0 = cnt[t * NSL];
        int en0 = (t == BK - 1) ? rlen : cnt[(t + 1) * NSL];
        int deg = en0 - st0;
        if (node < n) {
            rs[node] = ebase + st0;
            rl[node] = deg;
            dinv[node] = rsqrtf((float)(deg + 1));
            if (sseg) {
                #pragma unroll
                for (int s = 0; s < NSL; ++s)
                    sseg[(size_t)node * NSL + s] = ebase + cnt[t * NSL + s];
            }
        }
    }
    __syncthreads();
    for (int j = t; j < rlen; j += 512) {          // scatter back sorted
        unsigned e = buf[j];
        int key = (int)((e >> 20) * NSL) + (int)((e & SMASK) >> SSH);
        int p = atomicAdd(&cnt[key], 1);
        staging[ebase + p] = e;
    }
}

// --- xs[s] = x[s] * dinv[s]: hoists the per-edge dinv multiply out of pull1 ---
__global__ __launch_bounds__(256) void k_scale(const float4* __restrict__ x4,
                                               const float* __restrict__ dinv,
                                               float4* __restrict__ xs4, int total) {
    int i = blockIdx.x * blockDim.x + threadIdx.x;
    if (i < total) {
        float dd = dinv[i / NF4];
        float4 v = x4[i];
        xs4[i] = make_float4(v.x * dd, v.y * dd, v.z * dd, v.w * dd);
    }
}

// --- pull conv1, slice-major pass sl (one kernel launch per slice; the stream
//     is the phase barrier). Quad-per-node: thread k owns float4 cols {k,k+4,8+k|k<2}.
//     During this pass all resident blocks gather only from xs slice sl (2.6 MB,
//     L2-resident by construction). ax holds running raw sums; pass 0 writes
//     (self-term folded), passes 1..6 RMW-add, pass 7 adds then applies dd. ---
__global__ __launch_bounds__(256) void k_pull1_pass(
        const unsigned* __restrict__ st, const int* __restrict__ sseg,
        const int* __restrict__ rs, const int* __restrict__ rl,
        const float* __restrict__ dinv, const float4* __restrict__ xs4,
        float4* __restrict__ ax4, int n, int sl) {
    int gtid = blockIdx.x * 256 + threadIdx.x;
    int nd = gtid >> 2, k = gtid & 3;
    if (nd >= n) return;
    int q0 = k, q1 = k + 4, q2 = 8 + k;
    bool hq2 = (k < 2);

    int beg = sseg[(size_t)nd * NSL + sl];
    int end = (sl == NSL - 1) ? rs[nd] + rl[nd] : sseg[(size_t)nd * NSL + sl + 1];

    float4 z = make_float4(0.f, 0.f, 0.f, 0.f);
    float4 a0 = z, a1 = z, a2 = z;
    int j = beg;
    for (; j + 1 < end; j += 2) {                  // 2 edges x 2-3 independent gathers
        int s0 = (int)(st[j] & SMASK), s1 = (int)(st[j + 1] & SMASK);
        const float4* r0 = xs4 + (size_t)s0 * NF4;
        const float4* r1 = xs4 + (size_t)s1 * NF4;
        add4b(a0, r0[q0], r1[q0]);
        add4b(a1, r0[q1], r1[q1]);
        if (hq2) add4b(a2, r0[q2], r1[q2]);
    }
    if (j < end) {
        const float4* r0 = xs4 + (size_t)(st[j] & SMASK) * NF4;
        add4(a0, r0[q0]);
        add4(a1, r0[q1]);
        if (hq2) add4(a2, r0[q2]);
    }

    float4* axr = ax4 + (size_t)nd * NF4;
    const float4* xsr = xs4 + (size_t)nd * NF4;
    if (sl == 0) {                                 // init: self-term + slice0 sum
        add4(a0, xsr[q0]); axr[q0] = a0;
        add4(a1, xsr[q1]); axr[q1] = a1;
        if (hq2) { add4(a2, xsr[q2]); axr[q2] = a2; }
    } else if (sl == NSL - 1) {                    // finalize: dd * (prev + slice7 sum)
        float dd = dinv[nd];
        float4 p0 = axr[q0], p1 = axr[q1];
        axr[q0] = fin4(dd, a0, p0);
        axr[q1] = fin4(dd, a1, p1);
        if (hq2) { float4 p2 = axr[q2]; axr[q2] = fin4(dd, a2, p2); }
    } else if (beg < end) {                        // RMW-add (skip if empty segment)
        float4 p0 = axr[q0]; add4(a0, p0); axr[q0] = a0;
        float4 p1 = axr[q1]; add4(a1, p1); axr[q1] = a1;
        if (hq2) { float4 p2 = axr[q2]; add4(a2, p2); axr[q2] = a2; }
    }
}

// --- pull conv1 (xs fallback): 6 nbr slots x 10 lanes ---
__global__ __launch_bounds__(256) void k_pull1_xs(
        const unsigned* __restrict__ st, const int* __restrict__ rs,
        const int* __restrict__ rl, const float* __restrict__ dinv,
        const float4* __restrict__ xs4, float4* __restrict__ ax4, int n) {
    __shared__ float4 red[4][64];
    int t = threadIdx.x;
    int w = t >> 6, lane = t & 63;
    int d = blockIdx.x * 4 + w;
    if (d >= n) return;
    int g = lane / 10, f = lane - g * 10;
    int beg = rs[d], len = rl[d];
    float dd = dinv[d];
    float4 acc = make_float4(0.f, 0.f, 0.f, 0.f);
    if (g < 6) {
        int j = beg + g, end = beg + len;
        for (; j + 6 < end; j += 12) {
            unsigned eA = st[j], eB = st[j + 6];
            float4 a4 = xs4[(eA & SMASK) * NF4 + f];
            float4 b4 = xs4[(eB & SMASK) * NF4 + f];
            add4b(acc, a4, b4);
        }
        if (j < end) add4(acc, xs4[(st[j] & SMASK) * NF4 + f]);
    }
    red[w][lane] = acc;
    if (lane < NF4) {
        float4 tot = red[w][lane];
        #pragma unroll
        for (int gg = 1; gg < 6; ++gg) add4(tot, red[w][gg * 10 + lane]);
        ax4[d * NF4 + lane] = fin4(dd, tot, xs4[d * NF4 + lane]);
    }
}

// --- pull conv1 (no-xs fallback): dinv gathered per edge ---
__global__ __launch_bounds__(256) void k_pull1_od(
        const unsigned* __restrict__ st, const int* __restrict__ rs,
        const int* __restrict__ rl, const float* __restrict__ dinv,
        const float4* __restrict__ x4, float4* __restrict__ ax4, int n) {
    __shared__ float4 red[4][64];
    int t = threadIdx.x;
    int w = t >> 6, lane = t & 63;
    int d = blockIdx.x * 4 + w;
    if (d >= n) return;
    int g = lane / 10, f = lane - g * 10;
    int beg = rs[d], len = rl[d];
    float dd = dinv[d];
    float4 acc = make_float4(0.f, 0.f, 0.f, 0.f);
    if (g < 6) {
        int j = beg + g, end = beg + len;
        for (; j + 6 < end; j += 12) {
            unsigned eA = st[j], eB = st[j + 6];
            int sA = (int)(eA & SMASK), sB = (int)(eB & SMASK);
            float wA = dinv[sA], wB = dinv[sB];
            float4 a4 = x4[sA * NF4 + f];
            float4 b4 = x4[sB * NF4 + f];
            acc.x += a4.x * wA + b4.x * wB;
            acc.y += a4.y * wA + b4.y * wB;
            acc.z += a4.z * wA + b4.z * wB;
            acc.w += a4.w * wA + b4.w * wB;
        }
        if (j < end) {
            unsigned e = st[j];
            int s = (int)(e & SMASK);
            float wv = dinv[s];
            float4 v = x4[s * NF4 + f];
            acc.x += v.x * wv; acc.y += v.y * wv;
            acc.z += v.z * wv; acc.w += v.w * wv;
        }
    }
    red[w][lane] = acc;
    if (lane < NF4) {
        float4 tot = red[w][lane];
        #pragma unroll
        for (int gg = 1; gg < 6; ++gg) add4(tot, red[w][gg * 10 + lane]);
        float4 self = x4[d * NF4 + lane];
        float4 o;
        o.x = dd * (tot.x + self.x * dd);
        o.y = dd * (tot.y + self.y * dd);
        o.z = dd * (tot.z + self.z * dd);
        o.w = dd * (tot.w + self.w * dd);
        ax4[d * NF4 + lane] = o;
    }
}

// --- fused per-node MLP: register-tiled wave-GEMM, 32 nodes x 64 cols per wave ---
__global__ __launch_bounds__(256, 2) void k_node(
        const float4* __restrict__ ax4,
        const float* __restrict__ W1, const float* __restrict__ b1,
        const float* __restrict__ Wf, const float* __restrict__ bf,
        const float* __restrict__ W2, const float* __restrict__ dinv,
        float4* __restrict__ s2sp4, int n) {
    __shared__ float lW1[NF * H];
    __shared__ float lWf[H * H];
    __shared__ float hT[4][H * 32];
    int t = threadIdx.x, w = t >> 6, lane = t & 63;
    int r = lane & 7, c = lane >> 3;

    for (int i = t; i < NF * H; i += 256) lW1[i] = W1[i];
    for (int i = t; i < H * H;  i += 256) lWf[i] = Wf[i];
    __syncthreads();

    int nb0 = (blockIdx.x * 4 + w) * 32;
    if (nb0 >= n) return;
    int cnt = min(32, n - nb0);

    float bb[8], bfv[8], w2s[8][3];
    #pragma unroll
    for (int j = 0; j < 8; ++j) {
        bb[j]  = b1[8 * c + j];
        bfv[j] = bf[8 * c + j];
        w2s[j][0] = W2[(8 * c + j) * NC + 0];
        w2s[j][1] = W2[(8 * c + j) * NC + 1];
        w2s[j][2] = W2[(8 * c + j) * NC + 2];
    }

    float* axT = &hT[w][0];
    #pragma unroll
    for (int i = 0; i < 5; ++i) {
        int idx = lane + 64 * i;
        int no = idx / NF4, q = idx - no * NF4;
        float4 a = make_float4(0.f, 0.f, 0.f, 0.f);
        if (no < cnt) a = ax4[(size_t)(nb0 + no) * NF4 + q];
        axT[(4 * q + 0) * 32 + no] = a.x;
        axT[(4 * q + 1) * 32 + no] = a.y;
        axT[(4 * q + 2) * 32 + no] = a.z;
        axT[(4 * q + 3) * 32 + no] = a.w;
    }

    float acc[4][8];
    #pragma unroll
    for (int i = 0; i < 4; ++i)
        #pragma unroll
        for (int j = 0; j < 8; ++j) acc[i][j] = bb[j];
    for (int k = 0; k < NF; ++k) {
        float4 a   = *(const float4*)&axT[k * 32 + 4 * r];
        float4 blo = *(const float4*)&lW1[k * H + 8 * c];
        float4 bhi = *(const float4*)&lW1[k * H + 8 * c + 4];
        float av[4] = {a.x, a.y, a.z, a.w};
        float bv[8] = {blo.x, blo.y, blo.z, blo.w, bhi.x, bhi.y, bhi.z, bhi.w};
        #pragma unroll
        for (int i = 0; i < 4; ++i)
            #pragma unroll
            for (int j = 0; j < 8; ++j) acc[i][j] = fmaf(av[i], bv[j], acc[i][j]);
    }
    #pragma unroll
    for (int j = 0; j < 8; ++j) {
        float4 hv = make_float4(fmaxf(acc[0][j], 0.f), fmaxf(acc[1][j], 0.f),
                                fmaxf(acc[2][j], 0.f), fmaxf(acc[3][j], 0.f));
        *(float4*)&hT[w][(8 * c + j) * 32 + 4 * r] = hv;
    }

    float acc2[4][8];
    #pragma unroll
    for (int i = 0; i < 4; ++i)
        #pragma unroll
        for (int j = 0; j < 8; ++j) acc2[i][j] = bfv[j];
    for (int k = 0; k < H; ++k) {
        float4 a   = *(const float4*)&hT[w][k * 32 + 4 * r];
        float4 blo = *(const float4*)&lWf[k * H + 8 * c];
        float4 bhi = *(const float4*)&lWf[k * H + 8 * c + 4];
        float av[4] = {a.x, a.y, a.z, a.w};
        float bv[8] = {blo.x, blo.y, blo.z, blo.w, bhi.x, bhi.y, bhi.z, bhi.w};
        #pragma unroll
        for (int i = 0; i < 4; ++i)
            #pragma unroll
            for (int j = 0; j < 8; ++j) acc2[i][j] = fmaf(av[i], bv[j], acc2[i][j]);
    }

    float p0[4], p1[4], p2[4];
    #pragma unroll
    for (int i = 0; i < 4; ++i) { p0[i] = 0.f; p1[i] = 0.f; p2[i] = 0.f; }
    #pragma unroll
    for (int i = 0; i < 4; ++i)
        #pragma unroll
        for (int j = 0; j < 8; ++j) {
            float s = (acc2[i][j] >= 0.5f) ? 1.f : 0.f;
            p0[i] = fmaf(s, w2s[j][0], p0[i]);
            p1[i] = fmaf(s, w2s[j][1], p1[i]);
            p2[i] = fmaf(s, w2s[j][2], p2[i]);
        }
    #pragma unroll
    for (int off = 8; off < 64; off <<= 1) {
        #pragma unroll
        for (int i = 0; i < 4; ++i) {
            p0[i] += __shfl_xor(p0[i], off);
            p1[i] += __shfl_xor(p1[i], off);
            p2[i] += __shfl_xor(p2[i], off);
        }
    }
    if (c == 0) {
        #pragma unroll
        for (int i = 0; i < 4; ++i) {
            int no = 4 * r + i;
            if (no < cnt) {
                int node = nb0 + no;
                float di = dinv[node];
                s2sp4[node] = make_float4(p0[i] * di, p1[i] * di, p2[i] * di, 0.f);
            }
        }
    }
}

// --- pull conv2 + bias + filter ---
__global__ __launch_bounds__(256) void k_pull2(
        const unsigned* __restrict__ st, const int* __restrict__ rs,
        const int* __restrict__ rl, const float* __restrict__ dinv,
        const float4* __restrict__ s2sp4, const float* __restrict__ b2,
        const float* __restrict__ ef, float* __restrict__ out, int n) {
    int t = threadIdx.x;
    int w = t >> 6, lane = t & 63;
    int d = blockIdx.x * 4 + w;
    if (d >= n) return;
    int beg = rs[d], end = beg + rl[d];
    float a0 = 0.f, a1 = 0.f, a2 = 0.f;
    for (int j = beg + lane; j < end; j += 64) {
        float4 v = s2sp4[st[j] & SMASK];
        a0 += v.x; a1 += v.y; a2 += v.z;
    }
    for (int off = 32; off; off >>= 1) {
        a0 += __shfl_down(a0, off);
        a1 += __shfl_down(a1, off);
        a2 += __shfl_down(a2, off);
    }
    if (lane == 0) {
        float dd = dinv[d];
        float4 self = s2sp4[d];
        out[d * NC + 0] = (dd * (a0 + self.x) + b2[0]) * ef[0];
        out[d * NC + 1] = (dd * (a1 + self.y) + b2[1]) * ef[1];
        out[d * NC + 2] = (dd * (a2 + self.z) + b2[2]) * ef[2];
    }
}

extern "C" void kernel_launch(void* const* d_in, const int* in_sizes, int n_in,
                              void* d_out, int out_size, void* d_ws, size_t ws_size,
                              hipStream_t stream) {
    const float* x  = (const float*)d_in[0];
    const int*   ei = (const int*)d_in[1];
    const float* W1 = (const float*)d_in[2];
    const float* b1 = (const float*)d_in[3];
    const float* Wf = (const float*)d_in[4];
    const float* bf = (const float*)d_in[5];
    const float* W2 = (const float*)d_in[6];
    const float* b2 = (const float*)d_in[7];
    const float* ef = (const float*)d_in[8];

    int n  = in_sizes[0] / NF;
    int ne = in_sizes[1] / 2;
    const int* src = ei;
    const int* dst = ei + ne;
    int nbk = (n + BK - 1) >> 8;                   // 391

    auto al = [](size_t v) { return (v + 255) & ~(size_t)255; };
    char* ws = (char*)d_ws;
    size_t off = 0;
    unsigned* staging = (unsigned*)(ws + off); off += al((size_t)nbk * CAP * 4);   // 16 MB
    float*    axbuf   = (float*)(ws + off);    off += al((size_t)n * NF * 4);      // 16 MB
    float*    s2sp    = (float*)(ws + off);    off += al((size_t)n * 4 * 4);
    float*    dinv    = (float*)(ws + off);    off += al((size_t)n * 4);
    int*      rsb     = (int*)(ws + off);      off += al((size_t)n * 4);
    int*      rlb     = (int*)(ws + off);      off += al((size_t)n * 4);
    int*      gcur    = (int*)(ws + off);      off += al((size_t)MAXNBK * 4);
    float*    xsbuf   = (float*)(ws + off);
    size_t    need_xs = off + al((size_t)n * NF * 4);                              // ~51 MB
    int*      ssegb   = (int*)(ws + need_xs);
    size_t    need_cp = need_xs + al((size_t)n * NSL * 4);                         // ~54 MB
    bool use_xs   = (ws_size >= need_xs);
    bool use_coop = (ws_size >= need_cp);
    float* out = (float*)d_out;

    int binblocks = (ne + EPB - 1) / EPB;          // 500

    k_zero <<<2, 256, 0, stream>>>(gcur, MAXNBK);
    k_bin2 <<<binblocks, 512, 0, stream>>>(src, dst, gcur, staging, ne, nbk);
    k_sort <<<nbk, 512, 0, stream>>>(staging, gcur, rsb, rlb, dinv,
                                     use_coop ? ssegb : (int*)nullptr, n);
    if (use_coop) {
        k_scale<<<(n * NF4 + 255) / 256, 256, 0, stream>>>((const float4*)x, dinv,
                                                           (float4*)xsbuf, n * NF4);
        int pb = (4 * n + 255) / 256;              // quad-per-node
        for (int sl = 0; sl < NSL; ++sl)
            k_pull1_pass<<<pb, 256, 0, stream>>>(staging, ssegb, rsb, rlb, dinv,
                                                 (const float4*)xsbuf, (float4*)axbuf,
                                                 n, sl);
    } else if (use_xs) {
        k_scale  <<<(n * NF4 + 255) / 256, 256, 0, stream>>>((const float4*)x, dinv,
                                                             (float4*)xsbuf, n * NF4);
        k_pull1_xs<<<(n + 3) / 4, 256, 0, stream>>>(staging, rsb, rlb, dinv,
                                                    (const float4*)xsbuf,
                                                    (float4*)axbuf, n);
    } else {
        k_pull1_od<<<(n + 3) / 4, 256, 0, stream>>>(staging, rsb, rlb, dinv,
                                                    (const float4*)x, (float4*)axbuf, n);
    }
    k_node <<<(n + 127) / 128, 256, 0, stream>>>(
        (const float4*)axbuf, W1, b1, Wf, bf, W2, dinv, (float4*)s2sp, n);
    k_pull2<<<(n + 3) / 4, 256, 0, stream>>>(staging, rsb, rlb, dinv, (const float4*)s2sp,
                                             b2, ef, out, n);
}

// Round 15
// 221.374 us; speedup vs baseline: 2.4164x; 1.1507x over previous
//
#include <hip/hip_runtime.h>

#define NF 40
#define NF4 10
#define H  64
#define NC 3
#define BK 256        // nodes per bucket (dst>>8)
#define CAP 10240     // staging capacity per bucket (mean 8192, +22 sigma)
#define MAXNBK 512
#define SMASK 0xFFFFFu
#define EPB 6400      // edges per k_bin2 block

__device__ __forceinline__ void add4(float4& a, const float4& u) {
    a.x += u.x; a.y += u.y; a.z += u.z; a.w += u.w;
}

// --- zero ints ---
__global__ void k_zero(int* __restrict__ p, int n) {
    int i = blockIdx.x * blockDim.x + threadIdx.x;
    if (i < n) p[i] = 0;
}

// --- partition: block-local bucket sort in LDS, then coalesced window writes ---
__global__ __launch_bounds__(512) void k_bin2(const int* __restrict__ src,
                                              const int* __restrict__ dst,
                                              int* __restrict__ gcur,
                                              unsigned* __restrict__ staging,
                                              int ne, int nbk) {
    __shared__ unsigned sorted[EPB];               // 25.6 KB
    __shared__ unsigned short sbk[EPB];            // 12.8 KB
    __shared__ int cnt[MAXNBK];
    __shared__ int tsum[MAXNBK];
    __shared__ int lstart[MAXNBK];
    __shared__ int gbase[MAXNBK];
    __shared__ int cur[MAXNBK];
    int t = threadIdx.x;
    int e0 = blockIdx.x * EPB;
    int m = min(EPB, ne - e0);
    if (m <= 0) return;

    for (int b = t; b < MAXNBK; b += 512) cnt[b] = 0;
    __syncthreads();
    for (int j = t; j < m; j += 512)               // pass 1: bucket histogram
        atomicAdd(&cnt[dst[e0 + j] >> 8], 1);
    __syncthreads();
    int val = (t < nbk) ? cnt[t] : 0;              // block-wide exclusive scan (512)
    tsum[t] = val;
    __syncthreads();
    for (int off = 1; off < 512; off <<= 1) {
        int a = (t >= off) ? tsum[t - off] : 0;
        __syncthreads();
        tsum[t] += a;
        __syncthreads();
    }
    lstart[t] = tsum[t] - val;
    cur[t] = tsum[t] - val;
    if (t < nbk) gbase[t] = val ? atomicAdd(&gcur[t], val) : 0;   // reserve windows
    __syncthreads();
    for (int j = t; j < m; j += 512) {             // pass 2: LDS scatter (bucket order)
        int d = dst[e0 + j], s = src[e0 + j];
        int b = d >> 8;
        int p = atomicAdd(&cur[b], 1);
        sorted[p] = ((unsigned)(d & 255) << 20) | (unsigned)s;
        sbk[p] = (unsigned short)b;
    }
    __syncthreads();
    for (int j = t; j < m; j += 512) {             // pass 3: near-coalesced writes
        int b = sbk[j];
        staging[(size_t)b * CAP + gbase[b] + (j - lstart[b])] = sorted[j];
    }
}

// --- per-bucket sort by dlocal (in place via LDS bounce); emits rs/rl/dinv ---
__global__ __launch_bounds__(512) void k_sort(unsigned* __restrict__ staging,
                                              const int* __restrict__ gcur,
                                              int* __restrict__ rs, int* __restrict__ rl,
                                              float* __restrict__ dinv, int n) {
    __shared__ unsigned buf[CAP];      // 40 KB bounce buffer
    __shared__ int cnt[BK];
    __shared__ int scn[BK];
    __shared__ int cur[BK];
    int b = blockIdx.x, t = threadIdx.x;
    int ebase = b * CAP;
    int rlen = gcur[b];
    for (int j = t; j < rlen; j += 512) buf[j] = staging[ebase + j];
    if (t < BK) cnt[t] = 0;
    __syncthreads();
    for (int j = t; j < rlen; j += 512)
        atomicAdd(&cnt[buf[j] >> 20], 1);
    __syncthreads();
    if (t < BK) scn[t] = cnt[t];
    __syncthreads();
    for (int off = 1; off < BK; off <<= 1) {       // inclusive Hillis-Steele
        int a = (t < BK && t >= off) ? scn[t - off] : 0;
        __syncthreads();
        if (t < BK) scn[t] += a;
        __syncthreads();
    }
    if (t < BK) {
        int deg = cnt[t];
        int excl = scn[t] - deg;
        cur[t] = excl;
        int node = b * BK + t;
        if (node < n) {
            rs[node] = ebase + excl;
            rl[node] = deg;
            dinv[node] = rsqrtf((float)(deg + 1));
        }
    }
    __syncthreads();
    for (int j = t; j < rlen; j += 512) {          // scatter back sorted by dlocal
        unsigned e = buf[j];
        int p = atomicAdd(&cur[e >> 20], 1);
        staging[ebase + p] = e;
    }
}

// --- pull conv1: ax[d] = dd*(sum_s x[s]*dinv[s] + x[d]*dd); 6 nbr slots x 10 lanes ---
__global__ __launch_bounds__(256) void k_pull1(
        const unsigned* __restrict__ st, const int* __restrict__ rs,
        const int* __restrict__ rl, const float* __restrict__ dinv,
        const float4* __restrict__ x4, float4* __restrict__ ax4, int n) {
    __shared__ float4 red[4][64];
    int t = threadIdx.x;
    int w = t >> 6, lane = t & 63;
    int d = blockIdx.x * 4 + w;
    if (d >= n) return;
    int g = lane / 10, f = lane - g * 10;          // 6 slots x 10 float4-lanes
    int beg = rs[d], len = rl[d];
    float dd = dinv[d];
    float4 acc = make_float4(0.f, 0.f, 0.f, 0.f);
    if (g < 6) {
        int j = beg + g, end = beg + len;
        for (; j + 6 < end; j += 12) {             // 2 independent gathers in flight
            unsigned eA = st[j], eB = st[j + 6];
            int sA = (int)(eA & SMASK), sB = (int)(eB & SMASK);
            float wA = dinv[sA], wB = dinv[sB];
            float4 a4 = x4[sA * NF4 + f];
            float4 b4 = x4[sB * NF4 + f];
            acc.x += a4.x * wA + b4.x * wB;
            acc.y += a4.y * wA + b4.y * wB;
            acc.z += a4.z * wA + b4.z * wB;
            acc.w += a4.w * wA + b4.w * wB;
        }
        if (j < end) {
            unsigned e = st[j];
            int s = (int)(e & SMASK);
            float wv = dinv[s];
            float4 v = x4[s * NF4 + f];
            acc.x += v.x * wv; acc.y += v.y * wv;
            acc.z += v.z * wv; acc.w += v.w * wv;
        }
    }
    red[w][lane] = acc;
    // same-wave LDS RAW: in-order DS pipe + compiler lgkmcnt; no block barrier needed
    if (lane < NF4) {
        float4 tot = red[w][lane];
        #pragma unroll
        for (int gg = 1; gg < 6; ++gg) add4(tot, red[w][gg * 10 + lane]);
        float4 self = x4[d * NF4 + lane];
        float4 o;
        o.x = dd * (tot.x + self.x * dd);
        o.y = dd * (tot.y + self.y * dd);
        o.z = dd * (tot.z + self.z * dd);
        o.w = dd * (tot.w + self.w * dd);
        ax4[d * NF4 + lane] = o;
    }
}

// --- fused per-node MLP v3: register-tiled wave-GEMM, weights read from GLOBAL ---
// LDS = hT only (32 KB/block, per-wave private) -> 5 blocks/CU instead of 2.
// W1/Wf are 26 KB total, broadcast across all waves on a CU -> L1-resident.
// lane=(r,c): owns nodes 4r..4r+3, cols 8c..8c+7; acc[4][8].
__global__ __launch_bounds__(256) void k_node(
        const float4* __restrict__ ax4,
        const float* __restrict__ W1, const float* __restrict__ b1,
        const float* __restrict__ Wf, const float* __restrict__ bf,
        const float* __restrict__ W2, const float* __restrict__ dinv,
        float4* __restrict__ s2sp4, int n) {
    __shared__ float hT[4][H * 32];                // 8 KB/wave; low NF*32 doubles as axT
    int t = threadIdx.x, w = t >> 6, lane = t & 63;
    int r = lane & 7, c = lane >> 3;

    int nb0 = (blockIdx.x * 4 + w) * 32;
    if (nb0 >= n) return;                          // no block barrier anywhere: safe
    int cnt = min(32, n - nb0);

    float bb[8], bfv[8], w2s[8][3];
    #pragma unroll
    for (int j = 0; j < 8; ++j) {
        bb[j]  = b1[8 * c + j];
        bfv[j] = bf[8 * c + j];
        w2s[j][0] = W2[(8 * c + j) * NC + 0];
        w2s[j][1] = W2[(8 * c + j) * NC + 1];
        w2s[j][2] = W2[(8 * c + j) * NC + 2];
    }

    // stage ax rows (coalesced float4) transposed into axT[k][node] (= hT[w] low)
    float* axT = &hT[w][0];
    #pragma unroll
    for (int i = 0; i < 5; ++i) {
        int idx = lane + 64 * i;                   // 0..319 = 32 nodes x 10 float4
        int no = idx / NF4, q = idx - no * NF4;
        float4 a = make_float4(0.f, 0.f, 0.f, 0.f);
        if (no < cnt) a = ax4[(size_t)(nb0 + no) * NF4 + q];
        axT[(4 * q + 0) * 32 + no] = a.x;
        axT[(4 * q + 1) * 32 + no] = a.y;
        axT[(4 * q + 2) * 32 + no] = a.z;
        axT[(4 * q + 3) * 32 + no] = a.w;
    }
    // same-wave in-order DS: k-loop reads below see the staging writes

    // ---- layer 1: h = relu(ax*W1 + b1), K=40; W1 from global (L1-hot) ----
    float acc[4][8];
    #pragma unroll
    for (int i = 0; i < 4; ++i)
        #pragma unroll
        for (int j = 0; j < 8; ++j) acc[i][j] = bb[j];
    for (int k = 0; k < NF; ++k) {
        float4 a   = *(const float4*)&axT[k * 32 + 4 * r];
        float4 blo = *(const float4*)&W1[k * H + 8 * c];
        float4 bhi = *(const float4*)&W1[k * H + 8 * c + 4];
        float av[4] = {a.x, a.y, a.z, a.w};
        float bv[8] = {blo.x, blo.y, blo.z, blo.w, bhi.x, bhi.y, bhi.z, bhi.w};
        #pragma unroll
        for (int i = 0; i < 4; ++i)
            #pragma unroll
            for (int j = 0; j < 8; ++j) acc[i][j] = fmaf(av[i], bv[j], acc[i][j]);
    }
    // write h transposed (hT[col][node]); all L1 reads completed (program order)
    #pragma unroll
    for (int j = 0; j < 8; ++j) {
        float4 hv = make_float4(fmaxf(acc[0][j], 0.f), fmaxf(acc[1][j], 0.f),
                                fmaxf(acc[2][j], 0.f), fmaxf(acc[3][j], 0.f));
        *(float4*)&hT[w][(8 * c + j) * 32 + 4 * r] = hv;
    }

    // ---- layer 2: mem = h*Wf + bf, K=64; Wf from global (L1-hot) ----
    float acc2[4][8];
    #pragma unroll
    for (int i = 0; i < 4; ++i)
        #pragma unroll
        for (int j = 0; j < 8; ++j) acc2[i][j] = bfv[j];
    for (int k = 0; k < H; ++k) {
        float4 a   = *(const float4*)&hT[w][k * 32 + 4 * r];
        float4 blo = *(const float4*)&Wf[k * H + 8 * c];
        float4 bhi = *(const float4*)&Wf[k * H + 8 * c + 4];
        float av[4] = {a.x, a.y, a.z, a.w};
        float bv[8] = {blo.x, blo.y, blo.z, blo.w, bhi.x, bhi.y, bhi.z, bhi.w};
        #pragma unroll
        for (int i = 0; i < 4; ++i)
            #pragma unroll
            for (int j = 0; j < 8; ++j) acc2[i][j] = fmaf(av[i], bv[j], acc2[i][j]);
    }

    // ---- spike + W2: per-lane partials over its 8 cols, xor-reduce over c ----
    float p0[4], p1[4], p2[4];
    #pragma unroll
    for (int i = 0; i < 4; ++i) { p0[i] = 0.f; p1[i] = 0.f; p2[i] = 0.f; }
    #pragma unroll
    for (int i = 0; i < 4; ++i)
        #pragma unroll
        for (int j = 0; j < 8; ++j) {
            float s = (acc2[i][j] >= 0.5f) ? 1.f : 0.f;
            p0[i] = fmaf(s, w2s[j][0], p0[i]);
            p1[i] = fmaf(s, w2s[j][1], p1[i]);
            p2[i] = fmaf(s, w2s[j][2], p2[i]);
        }
    #pragma unroll
    for (int off = 8; off < 64; off <<= 1) {
        #pragma unroll
        for (int i = 0; i < 4; ++i) {
            p0[i] += __shfl_xor(p0[i], off);
            p1[i] += __shfl_xor(p1[i], off);
            p2[i] += __shfl_xor(p2[i], off);
        }
    }
    if (c == 0) {
        #pragma unroll
        for (int i = 0; i < 4; ++i) {
            int no = 4 * r + i;
            if (no < cnt) {
                int node = nb0 + no;
                float di = dinv[node];
                s2sp4[node] = make_float4(p0[i] * di, p1[i] * di, p2[i] * di, 0.f);
            }
        }
    }
}

// --- pull conv2 + bias + filter; one float4 gather per neighbor ---
__global__ __launch_bounds__(256) void k_pull2(
        const unsigned* __restrict__ st, const int* __restrict__ rs,
        const int* __restrict__ rl, const float* __restrict__ dinv,
        const float4* __restrict__ s2sp4, const float* __restrict__ b2,
        const float* __restrict__ ef, float* __restrict__ out, int n) {
    int t = threadIdx.x;
    int w = t >> 6, lane = t & 63;
    int d = blockIdx.x * 4 + w;
    if (d >= n) return;
    int beg = rs[d], end = beg + rl[d];
    float a0 = 0.f, a1 = 0.f, a2 = 0.f;
    for (int j = beg + lane; j < end; j += 64) {
        float4 v = s2sp4[st[j] & SMASK];           // 1.6 MB: L2-resident gather
        a0 += v.x; a1 += v.y; a2 += v.z;
    }
    for (int off = 32; off; off >>= 1) {
        a0 += __shfl_down(a0, off);
        a1 += __shfl_down(a1, off);
        a2 += __shfl_down(a2, off);
    }
    if (lane == 0) {
        float dd = dinv[d];
        float4 self = s2sp4[d];
        out[d * NC + 0] = (dd * (a0 + self.x) + b2[0]) * ef[0];
        out[d * NC + 1] = (dd * (a1 + self.y) + b2[1]) * ef[1];
        out[d * NC + 2] = (dd * (a2 + self.z) + b2[2]) * ef[2];
    }
}

extern "C" void kernel_launch(void* const* d_in, const int* in_sizes, int n_in,
                              void* d_out, int out_size, void* d_ws, size_t ws_size,
                              hipStream_t stream) {
    const float* x  = (const float*)d_in[0];
    const int*   ei = (const int*)d_in[1];
    const float* W1 = (const float*)d_in[2];
    const float* b1 = (const float*)d_in[3];
    const float* Wf = (const float*)d_in[4];
    const float* bf = (const float*)d_in[5];
    const float* W2 = (const float*)d_in[6];
    const float* b2 = (const float*)d_in[7];
    const float* ef = (const float*)d_in[8];

    int n  = in_sizes[0] / NF;
    int ne = in_sizes[1] / 2;
    const int* src = ei;
    const int* dst = ei + ne;
    int nbk = (n + BK - 1) >> 8;                   // 391

    auto al = [](size_t v) { return (v + 255) & ~(size_t)255; };
    char* ws = (char*)d_ws;
    size_t off = 0;
    unsigned* staging = (unsigned*)(ws + off); off += al((size_t)nbk * CAP * 4);   // 16 MB
    float*    axbuf   = (float*)(ws + off);    off += al((size_t)n * NF * 4);      // 16 MB
    float*    s2sp    = (float*)(ws + off);    off += al((size_t)n * 4 * 4);
    float*    dinv    = (float*)(ws + off);    off += al((size_t)n * 4);
    int*      rsb     = (int*)(ws + off);      off += al((size_t)n * 4);
    int*      rlb     = (int*)(ws + off);      off += al((size_t)n * 4);
    int*      gcur    = (int*)(ws + off);      off += al((size_t)MAXNBK * 4);
    float* out = (float*)d_out;

    int binblocks = (ne + EPB - 1) / EPB;          // 500

    k_zero <<<2, 256, 0, stream>>>(gcur, MAXNBK);
    k_bin2 <<<binblocks, 512, 0, stream>>>(src, dst, gcur, staging, ne, nbk);
    k_sort <<<nbk, 512, 0, stream>>>(staging, gcur, rsb, rlb, dinv, n);
    k_pull1<<<(n + 3) / 4, 256, 0, stream>>>(staging, rsb, rlb, dinv,
                                             (const float4*)x, (float4*)axbuf, n);
    k_node <<<(n + 127) / 128, 256, 0, stream>>>(
        (const float4*)axbuf, W1, b1, Wf, bf, W2, dinv, (float4*)s2sp, n);
    k_pull2<<<(n + 3) / 4, 256, 0, stream>>>(staging, rsb, rlb, dinv, (const float4*)s2sp,
                                             b2, ef, out, n);
}